// Round 22
// baseline (83.980 us; speedup 1.0000x reference)
//
#include <hip/hip_runtime.h>
#include <stdint.h>
#include <math.h>

#define CC 22
#define START_I 20
#define STOP_I 21
#define BB 64
#define LL 512
#define DD 512
#define NEGV -100000.0f
#define NCH 32
#define CS 16
#define WLD 520  // W lds row stride (bf16): conflict-free b128

// ws layout
#define EMIT_FLOATS ((BB * LL + CS) * CC)
#define BP_OFF (((EMIT_FLOATS * 4) + 255) & ~255)
#define BP_BYTES (BB * LL * CC)
#define META_OFF ((BP_OFF + BP_BYTES + 255) & ~255)
#define PV_OFF (META_OFF + 1024)
#define PHI_OFF (PV_OFF + BB * NCH * CC * 4)

typedef __attribute__((ext_vector_type(8))) short bf16x8;
typedef __attribute__((ext_vector_type(4))) float f32x4;

__device__ __forceinline__ unsigned short f2bf(float f) {  // RTNE f32->bf16
  unsigned u = __float_as_uint(f);
  return (unsigned short)((u + 0x7fffu + ((u >> 16) & 1u)) >> 16);
}

__device__ __forceinline__ bf16x8 pack8(float4 a, float4 b) {
  bf16x8 r;
  r[0] = (short)f2bf(a.x); r[1] = (short)f2bf(a.y);
  r[2] = (short)f2bf(a.z); r[3] = (short)f2bf(a.w);
  r[4] = (short)f2bf(b.x); r[5] = (short)f2bf(b.y);
  r[6] = (short)f2bf(b.z); r[7] = (short)f2bf(b.w);
  return r;
}

// ---------------- emissions GEMM via bf16 MFMA, register-direct A ----------------
__global__ __launch_bounds__(256) void k_emit(const float* __restrict__ x,
                                              const float* __restrict__ W,
                                              const float* __restrict__ bias,
                                              float* __restrict__ emit) {
  __shared__ unsigned short Wl[32 * WLD];  // 33,280 B
  const int tid = threadIdx.x;
  // stage W vectorized (c>=22 zero-padded)
#pragma unroll
  for (int it = 0; it < 16; ++it) {
    int g = it * 256 + tid;
    int c = g >> 7, d4 = g & 127;
    ushort4 pk;
    if (c < CC) {
      float4 v = ((const float4*)W)[c * 128 + d4];
      pk = make_ushort4(f2bf(v.x), f2bf(v.y), f2bf(v.z), f2bf(v.w));
    } else {
      pk = make_ushort4(0, 0, 0, 0);
    }
    *(ushort4*)&Wl[c * WLD + 4 * d4] = pk;
  }
  __syncthreads();

  const int lane = tid & 63;
  const int w = tid >> 6;
  const size_t wbase = (size_t)blockIdx.x * 64 + w * 16;  // wave's 16-row tile
  const int am = lane & 15;
  const int ag = lane >> 4;
  const float* xr = x + (wbase + am) * DD + ag * 8;  // lane's A-row, k-group
  f32x4 acc0 = {0.f, 0.f, 0.f, 0.f};
  f32x4 acc1 = {0.f, 0.f, 0.f, 0.f};

#pragma unroll
  for (int kc = 0; kc < 4; ++kc) {
#pragma unroll
    for (int s = 0; s < 4; ++s) {
      const int k0 = kc * 128 + s * 32;
      float4 v0 = *(const float4*)(xr + k0);
      float4 v1 = *(const float4*)(xr + k0 + 4);
      bf16x8 a = pack8(v0, v1);
      bf16x8 b0 = *(const bf16x8*)&Wl[am * WLD + k0 + ag * 8];
      bf16x8 b1 = *(const bf16x8*)&Wl[(am + 16) * WLD + k0 + ag * 8];
      acc0 = __builtin_amdgcn_mfma_f32_16x16x32_bf16(a, b0, acc0, 0, 0, 0);
      acc1 = __builtin_amdgcn_mfma_f32_16x16x32_bf16(a, b1, acc1, 0, 0, 0);
    }
  }

  const float bc0 = bias[am];
  const float bc1 = (am < 6) ? bias[am + 16] : 0.0f;
#pragma unroll
  for (int reg = 0; reg < 4; ++reg) {
    size_t row = wbase + 4 * ag + reg;
    emit[row * CC + am] = acc0[reg] + bc0;
    if (am < 6) emit[row * CC + am + 16] = acc1[reg] + bc1;
  }
}

__device__ __forceinline__ float rlf(float v, int l) {
  return __int_as_float(__builtin_amdgcn_readlane(__float_as_int(v), l));
}

// ---------------- segment transfer matrices (parallel-in-time Viterbi) ----------
__global__ __launch_bounds__(256) void k_seg(const float* __restrict__ emit,
                                             const float* __restrict__ mask,
                                             const float* __restrict__ trans,
                                             float* __restrict__ phi) {
  __shared__ float Ph[2][CC][23];
  __shared__ float els[CS * CC];
  const int seg = blockIdx.x, b = blockIdx.y;
  const int tid = threadIdx.x;
  const int lane = tid & 63;
  int n = 0;  // each wave computes redundantly (no sync needed)
#pragma unroll
  for (int k = 0; k < 8; ++k)
    n += __popcll(__ballot(mask[(size_t)b * LL + k * 64 + lane] > 0.0f));
  const int t0 = seg * CS;
  for (int i = tid; i < CS * CC; i += 256)  // full 352-entry fill
    els[i] = emit[((size_t)b * LL + t0) * CC + i];
  const bool own = tid < 242;
  const int to2 = own ? tid / CC : 0;   // 0..10
  const int frm0 = own ? tid % CC : 0;  // 0..21
  float T0[CC], T1[CC];
  if (own) {
#pragma unroll
    for (int f = 0; f < CC; ++f) {
      T0[f] = trans[to2 * CC + f];
      T1[f] = trans[(to2 + 11) * CC + f];
    }
    Ph[0][to2][frm0] = (to2 == frm0) ? 0.0f : -INFINITY;
    Ph[0][to2 + 11][frm0] = (to2 + 11 == frm0) ? 0.0f : -INFINITY;
  }
  __syncthreads();
  int steps = n - t0;
  steps = steps < 0 ? 0 : (steps > CS ? CS : steps);
  int c = 0;
  for (int q = 0; q < steps; ++q) {  // block-uniform trip count
    if (own) {
      float a0 = -INFINITY, a1 = -INFINITY;
#pragma unroll
      for (int f = 0; f < CC; ++f) {
        float v = Ph[c][f][frm0];
        a0 = fmaxf(a0, v + T0[f]);
        a1 = fmaxf(a1, v + T1[f]);
      }
      Ph[c ^ 1][to2][frm0] = a0 + els[q * CC + to2];
      Ph[c ^ 1][to2 + 11][frm0] = a1 + els[q * CC + to2 + 11];
    }
    __syncthreads();
    c ^= 1;
  }
  if (own) {
    float* pb = phi + ((size_t)b * NCH + seg) * CC * CC;
    pb[to2 * CC + frm0] = Ph[c][to2][frm0];
    pb[(to2 + 11) * CC + frm0] = Ph[c][to2 + 11][frm0];
  }
}

// ---------------- compose: 32 matrix-vector max-plus steps per batch ----------
__global__ __launch_bounds__(64, 1) void k_cmp(const float* __restrict__ phi,
                                               const float* __restrict__ mask,
                                               const float* __restrict__ trans,
                                               float* __restrict__ out_score,
                                               float* __restrict__ pv,
                                               int* __restrict__ meta) {
  const int b = blockIdx.x;
  const int lane = threadIdx.x;
  const int lc = lane < CC ? lane : CC - 1;
  const float Tstop = trans[STOP_I * CC + lc];
  int n = 0;
#pragma unroll
  for (int k = 0; k < 8; ++k)
    n += __popcll(__ballot(mask[(size_t)b * LL + k * 64 + lane] > 0.0f));

  float st = (lane == START_I) ? 0.0f : NEGV;
  const float* pb = phi + (size_t)b * NCH * CC * CC;
  float row[CC], nrow[CC];
#pragma unroll
  for (int f = 0; f < CC; ++f) row[f] = pb[lc * CC + f];
  for (int s = 0; s < NCH; ++s) {
    if (lane < CC) pv[((size_t)b * NCH + s) * CC + lane] = st;
    if (s + 1 < NCH) {
#pragma unroll
      for (int f = 0; f < CC; ++f) nrow[f] = pb[((s + 1) * CC + lc) * CC + f];
    }
    float a = -INFINITY;
#pragma unroll
    for (int f = 0; f < CC; ++f) a = fmaxf(a, row[f] + rlf(st, f));
    st = a;  // identity segments preserve st exactly
#pragma unroll
    for (int f = 0; f < CC; ++f) row[f] = nrow[f];
  }

  float fin = st + Tstop;
  if (lane < CC) out_score[b * CC + lane] = fin;
  float bv = -3.0e38f;
  int bt = 0;
#pragma unroll
  for (int k = 0; k < CC; ++k) {
    float v = rlf(fin, k);
    bool g = v > bv;
    bv = g ? v : bv;
    bt = g ? k : bt;
  }
  if (lane == 0) { meta[b] = n; meta[BB + b] = bt; }
}

// ---------------- parallel replay: backpointers from checkpoints ----------------
#define RSTEP(Q, EV)                                                        \
  {                                                                         \
    const bool act = (Q) < m;                                               \
    float g0 = rlf(st, 0) + T_0,   g1 = rlf(st, 1) + T_1;                   \
    float g2 = rlf(st, 2) + T_2,   g3 = rlf(st, 3) + T_3;                   \
    float g4 = rlf(st, 4) + T_4,   g5 = rlf(st, 5) + T_5;                   \
    float g6 = rlf(st, 6) + T_6,   g7 = rlf(st, 7) + T_7;                   \
    float g8 = rlf(st, 8) + T_8,   g9 = rlf(st, 9) + T_9;                   \
    float g10 = rlf(st, 10) + T_10, g11 = rlf(st, 11) + T_11;               \
    float g12 = rlf(st, 12) + T_12, g13 = rlf(st, 13) + T_13;               \
    float g14 = rlf(st, 14) + T_14, g15 = rlf(st, 15) + T_15;               \
    float g16 = rlf(st, 16) + T_16, g17 = rlf(st, 17) + T_17;               \
    float g18 = rlf(st, 18) + T_18, g19 = rlf(st, 19) + T_19;               \
    float g20 = rlf(st, 20) + T_20, g21 = rlf(st, 21) + T_21;               \
    float m0 = fmaxf(fmaxf(g0, g1), g2);                                    \
    float m1 = fmaxf(fmaxf(g3, g4), g5);                                    \
    float m2 = fmaxf(fmaxf(g6, g7), g8);                                    \
    float m3 = fmaxf(fmaxf(g9, g10), g11);                                  \
    float m4 = fmaxf(fmaxf(g12, g13), g14);                                 \
    float m5 = fmaxf(fmaxf(g15, g16), g17);                                 \
    float m6 = fmaxf(fmaxf(g18, g19), g20);                                 \
    float n0_ = fmaxf(fmaxf(m0, m1), m2);                                   \
    float n1_ = fmaxf(fmaxf(m3, m4), m5);                                   \
    float n2_ = fmaxf(m6, g21);                                             \
    float mx = fmaxf(fmaxf(n0_, n1_), n2_);                                 \
    unsigned u = (g0 == mx ? 1u : 0u) | (g1 == mx ? 2u : 0u) |              \
                 (g2 == mx ? 4u : 0u) | (g3 == mx ? 8u : 0u) |              \
                 (g4 == mx ? 16u : 0u) | (g5 == mx ? 32u : 0u) |            \
                 (g6 == mx ? 64u : 0u) | (g7 == mx ? 128u : 0u) |           \
                 (g8 == mx ? 256u : 0u) | (g9 == mx ? 512u : 0u) |          \
                 (g10 == mx ? 1024u : 0u) | (g11 == mx ? 2048u : 0u) |      \
                 (g12 == mx ? 4096u : 0u) | (g13 == mx ? 8192u : 0u) |      \
                 (g14 == mx ? 16384u : 0u) | (g15 == mx ? 32768u : 0u) |    \
                 (g16 == mx ? 65536u : 0u) | (g17 == mx ? 131072u : 0u) |   \
                 (g18 == mx ? 262144u : 0u) | (g19 == mx ? 524288u : 0u) |  \
                 (g20 == mx ? 1048576u : 0u) | (g21 == mx ? 2097152u : 0u); \
    if (act && lane < CC) bpo[(Q)*CC] = (unsigned char)__builtin_ctz(u);    \
    st = act ? (mx + (EV)) : st;                                            \
  }

__global__ __launch_bounds__(64, 1) void k_rep(const float* __restrict__ emit,
                                               const float* __restrict__ trans,
                                               const float* __restrict__ pv,
                                               const int* __restrict__ meta,
                                               unsigned char* __restrict__ bp) {
  const int c = blockIdx.x, b = blockIdx.y;
  const int lane = threadIdx.x;
  const int n = meta[b];
  const int t0 = c * CS;
  if (t0 >= n) return;
  const int lc = lane < CC ? lane : CC - 1;
  const float* tr = trans + lc * CC;
  float T_0 = tr[0], T_1 = tr[1], T_2 = tr[2], T_3 = tr[3], T_4 = tr[4];
  float T_5 = tr[5], T_6 = tr[6], T_7 = tr[7], T_8 = tr[8], T_9 = tr[9];
  float T_10 = tr[10], T_11 = tr[11], T_12 = tr[12], T_13 = tr[13];
  float T_14 = tr[14], T_15 = tr[15], T_16 = tr[16], T_17 = tr[17];
  float T_18 = tr[18], T_19 = tr[19], T_20 = tr[20], T_21 = tr[21];
  float st = pv[((size_t)b * NCH + c) * CC + lc];
  const float* ebl = emit + ((size_t)b * LL + t0) * CC + lc;
  float e0 = ebl[0 * CC], e1 = ebl[1 * CC], e2 = ebl[2 * CC], e3 = ebl[3 * CC];
  float e4 = ebl[4 * CC], e5 = ebl[5 * CC], e6 = ebl[6 * CC], e7 = ebl[7 * CC];
  float e8 = ebl[8 * CC], e9 = ebl[9 * CC], e10 = ebl[10 * CC], e11 = ebl[11 * CC];
  float e12 = ebl[12 * CC], e13 = ebl[13 * CC], e14 = ebl[14 * CC], e15 = ebl[15 * CC];
  asm volatile(""
               : "+v"(e0), "+v"(e1), "+v"(e2), "+v"(e3), "+v"(e4), "+v"(e5),
                 "+v"(e6), "+v"(e7), "+v"(e8), "+v"(e9), "+v"(e10), "+v"(e11),
                 "+v"(e12), "+v"(e13), "+v"(e14), "+v"(e15));
  asm volatile(""
               : "+v"(T_0), "+v"(T_1), "+v"(T_2), "+v"(T_3), "+v"(T_4),
                 "+v"(T_5), "+v"(T_6), "+v"(T_7), "+v"(T_8), "+v"(T_9),
                 "+v"(T_10), "+v"(T_11), "+v"(T_12), "+v"(T_13), "+v"(T_14),
                 "+v"(T_15), "+v"(T_16), "+v"(T_17), "+v"(T_18), "+v"(T_19),
                 "+v"(T_20), "+v"(T_21));
  unsigned char* bpo = bp + ((size_t)b * LL + t0) * CC + lane;
  const int m = (n - t0) < CS ? (n - t0) : CS;
  RSTEP(0, e0)   RSTEP(1, e1)   RSTEP(2, e2)   RSTEP(3, e3)
  RSTEP(4, e4)   RSTEP(5, e5)   RSTEP(6, e6)   RSTEP(7, e7)
  RSTEP(8, e8)   RSTEP(9, e9)   RSTEP(10, e10) RSTEP(11, e11)
  RSTEP(12, e12) RSTEP(13, e13) RSTEP(14, e14) RSTEP(15, e15)
}

// ---------------- backtrace: chunk-composed backpointer maps ----------------
__global__ __launch_bounds__(64, 1) void k_back(const unsigned char* __restrict__ bp,
                                                const int* __restrict__ meta,
                                                float* __restrict__ out_path) {
  __shared__ __align__(16) unsigned char bps[LL * CC];  // 11264 B
  __shared__ unsigned char gs[64 * CC];
  const int b = blockIdx.x, lane = threadIdx.x;
  const int n = meta[b];
  const int bt = meta[BB + b];
  const uint32_t* src = (const uint32_t*)(bp + (size_t)b * LL * CC);
  uint32_t* dst = (uint32_t*)bps;
  for (int i = lane; i < (LL * CC) / 4; i += 64) dst[i] = src[i];
  __syncthreads();
  const int k = lane;
  {
    int tg0 = 0, tg1 = 1, tg2 = 2, tg3 = 3, tg4 = 4, tg5 = 5, tg6 = 6,
        tg7 = 7, tg8 = 8, tg9 = 9, tg10 = 10, tg11 = 11, tg12 = 12, tg13 = 13,
        tg14 = 14, tg15 = 15, tg16 = 16, tg17 = 17, tg18 = 18, tg19 = 19,
        tg20 = 20, tg21 = 21;
#pragma unroll
    for (int j = 7; j >= 0; --j) {
      const int t = 8 * k + j;
      const bool act = t < n;
      const unsigned char* bt_ = bps + t * CC;
      int v0 = bt_[tg0], v1 = bt_[tg1], v2 = bt_[tg2], v3 = bt_[tg3];
      int v4 = bt_[tg4], v5 = bt_[tg5], v6 = bt_[tg6], v7 = bt_[tg7];
      int v8 = bt_[tg8], v9 = bt_[tg9], v10 = bt_[tg10], v11 = bt_[tg11];
      int v12 = bt_[tg12], v13 = bt_[tg13], v14 = bt_[tg14], v15 = bt_[tg15];
      int v16 = bt_[tg16], v17 = bt_[tg17], v18 = bt_[tg18], v19 = bt_[tg19];
      int v20 = bt_[tg20], v21 = bt_[tg21];
      tg0 = act ? v0 : tg0;   tg1 = act ? v1 : tg1;
      tg2 = act ? v2 : tg2;   tg3 = act ? v3 : tg3;
      tg4 = act ? v4 : tg4;   tg5 = act ? v5 : tg5;
      tg6 = act ? v6 : tg6;   tg7 = act ? v7 : tg7;
      tg8 = act ? v8 : tg8;   tg9 = act ? v9 : tg9;
      tg10 = act ? v10 : tg10; tg11 = act ? v11 : tg11;
      tg12 = act ? v12 : tg12; tg13 = act ? v13 : tg13;
      tg14 = act ? v14 : tg14; tg15 = act ? v15 : tg15;
      tg16 = act ? v16 : tg16; tg17 = act ? v17 : tg17;
      tg18 = act ? v18 : tg18; tg19 = act ? v19 : tg19;
      tg20 = act ? v20 : tg20; tg21 = act ? v21 : tg21;
    }
    unsigned char* go = gs + k * CC;
    go[0] = (unsigned char)tg0;   go[1] = (unsigned char)tg1;
    go[2] = (unsigned char)tg2;   go[3] = (unsigned char)tg3;
    go[4] = (unsigned char)tg4;   go[5] = (unsigned char)tg5;
    go[6] = (unsigned char)tg6;   go[7] = (unsigned char)tg7;
    go[8] = (unsigned char)tg8;   go[9] = (unsigned char)tg9;
    go[10] = (unsigned char)tg10; go[11] = (unsigned char)tg11;
    go[12] = (unsigned char)tg12; go[13] = (unsigned char)tg13;
    go[14] = (unsigned char)tg14; go[15] = (unsigned char)tg15;
    go[16] = (unsigned char)tg16; go[17] = (unsigned char)tg17;
    go[18] = (unsigned char)tg18; go[19] = (unsigned char)tg19;
    go[20] = (unsigned char)tg20; go[21] = (unsigned char)tg21;
  }
  __syncthreads();
  int tag = bt, entry = bt;
  for (int kk = 63; kk >= 0; --kk) {
    if (lane == kk) entry = tag;
    tag = gs[kk * CC + tag];
  }
  tag = entry;
  float* op = out_path + (size_t)b * LL;
#pragma unroll
  for (int j = 7; j >= 0; --j) {
    int t = 8 * k + j;
    bool act = t < n;
    op[t] = act ? (float)tag : 0.0f;
    int nv = bps[t * CC + tag];
    tag = act ? nv : tag;
  }
}

extern "C" void kernel_launch(void* const* d_in, const int* in_sizes, int n_in,
                              void* d_out, int out_size, void* d_ws, size_t ws_size,
                              hipStream_t stream) {
  const float* x = (const float*)d_in[0];
  const float* mask = (const float*)d_in[1];
  const float* W = (const float*)d_in[2];
  const float* bias = (const float*)d_in[3];
  const float* trans = (const float*)d_in[4];
  float* out_score = (float*)d_out;                 // [B, C] f32
  float* out_path = (float*)d_out + BB * CC;        // [B, L] as f32 values
  char* ws = (char*)d_ws;
  float* emit = (float*)ws;
  unsigned char* bp = (unsigned char*)(ws + BP_OFF);
  int* meta = (int*)(ws + META_OFF);
  float* pvp = (float*)(ws + PV_OFF);
  float* phi = (float*)(ws + PHI_OFF);

  k_emit<<<dim3((BB * LL) / 64), dim3(256), 0, stream>>>(x, W, bias, emit);
  // MEASUREMENT ROUND: k_seg launched twice (idempotent: same inputs -> same
  // phi bytes). Total-time delta vs round 20 (66.9 us) = k_seg wall time.
  k_seg<<<dim3(NCH, BB), dim3(256), 0, stream>>>(emit, mask, trans, phi);
  k_seg<<<dim3(NCH, BB), dim3(256), 0, stream>>>(emit, mask, trans, phi);
  k_cmp<<<dim3(BB), dim3(64), 0, stream>>>(phi, mask, trans, out_score, pvp, meta);
  k_rep<<<dim3(NCH, BB), dim3(64), 0, stream>>>(emit, trans, pvp, meta, bp);
  k_back<<<dim3(BB), dim3(64), 0, stream>>>(bp, meta, out_path);
}

// Round 23
// 66.632 us; speedup vs baseline: 1.2604x; 1.2604x over previous
//
#include <hip/hip_runtime.h>
#include <stdint.h>
#include <math.h>

#define CC 22
#define START_I 20
#define STOP_I 21
#define BB 64
#define LL 512
#define DD 512
#define NEGV -100000.0f
#define NCH 32
#define CS 16
#define WLD 520  // W lds row stride (bf16): conflict-free b128

// ws layout
#define EMIT_FLOATS ((BB * LL + CS) * CC)
#define BP_OFF (((EMIT_FLOATS * 4) + 255) & ~255)
#define BP_BYTES (BB * LL * CC)
#define META_OFF ((BP_OFF + BP_BYTES + 255) & ~255)
#define PV_OFF (META_OFF + 1024)
#define PHI_OFF (PV_OFF + BB * NCH * CC * 4)

typedef __attribute__((ext_vector_type(8))) short bf16x8;
typedef __attribute__((ext_vector_type(4))) float f32x4;

__device__ __forceinline__ unsigned short f2bf(float f) {  // RTNE f32->bf16
  unsigned u = __float_as_uint(f);
  return (unsigned short)((u + 0x7fffu + ((u >> 16) & 1u)) >> 16);
}

__device__ __forceinline__ bf16x8 pack8(float4 a, float4 b) {
  bf16x8 r;
  r[0] = (short)f2bf(a.x); r[1] = (short)f2bf(a.y);
  r[2] = (short)f2bf(a.z); r[3] = (short)f2bf(a.w);
  r[4] = (short)f2bf(b.x); r[5] = (short)f2bf(b.y);
  r[6] = (short)f2bf(b.z); r[7] = (short)f2bf(b.w);
  return r;
}

// ---------------- emissions GEMM via bf16 MFMA, register-direct A ----------------
// MLP restructure: issue ALL 32 independent x-loads first (in flight under the
// W staging + barrier), then convert+MFMA. Same per-output arithmetic order ->
// emit bit-identical (absmax stays 18). xv[] fully unrolled = static indices.
__global__ __launch_bounds__(256, 1) void k_emit(const float* __restrict__ x,
                                                 const float* __restrict__ W,
                                                 const float* __restrict__ bias,
                                                 float* __restrict__ emit) {
  __shared__ unsigned short Wl[32 * WLD];  // 33,280 B
  const int tid = threadIdx.x;
  const int lane = tid & 63;
  const int w = tid >> 6;
  const size_t wbase = (size_t)blockIdx.x * 64 + w * 16;  // wave's 16-row tile
  const int am = lane & 15;
  const int ag = lane >> 4;
  const float* xr = x + (wbase + am) * DD + ag * 8;  // lane's A-row, k-group

  // 1) issue all 32 x-loads (independent; vmcnt tracks them in flight)
  float4 xv[32];
#pragma unroll
  for (int i = 0; i < 16; ++i) {
    xv[2 * i] = *(const float4*)(xr + i * 32);
    xv[2 * i + 1] = *(const float4*)(xr + i * 32 + 4);
  }

  // 2) stage W (LDS work + barrier hide the x-load latency)
#pragma unroll
  for (int it = 0; it < 16; ++it) {
    int g = it * 256 + tid;
    int c = g >> 7, d4 = g & 127;
    ushort4 pk;
    if (c < CC) {
      float4 v = ((const float4*)W)[c * 128 + d4];
      pk = make_ushort4(f2bf(v.x), f2bf(v.y), f2bf(v.z), f2bf(v.w));
    } else {
      pk = make_ushort4(0, 0, 0, 0);
    }
    *(ushort4*)&Wl[c * WLD + 4 * d4] = pk;
  }
  __syncthreads();

  // 3) convert + MFMA (same kc->s order as prior rounds)
  f32x4 acc0 = {0.f, 0.f, 0.f, 0.f};
  f32x4 acc1 = {0.f, 0.f, 0.f, 0.f};
#pragma unroll
  for (int kc = 0; kc < 4; ++kc) {
#pragma unroll
    for (int s = 0; s < 4; ++s) {
      const int i = kc * 4 + s;
      const int k0 = kc * 128 + s * 32;
      bf16x8 a = pack8(xv[2 * i], xv[2 * i + 1]);
      bf16x8 b0 = *(const bf16x8*)&Wl[am * WLD + k0 + ag * 8];
      bf16x8 b1 = *(const bf16x8*)&Wl[(am + 16) * WLD + k0 + ag * 8];
      acc0 = __builtin_amdgcn_mfma_f32_16x16x32_bf16(a, b0, acc0, 0, 0, 0);
      acc1 = __builtin_amdgcn_mfma_f32_16x16x32_bf16(a, b1, acc1, 0, 0, 0);
    }
  }

  const float bc0 = bias[am];
  const float bc1 = (am < 6) ? bias[am + 16] : 0.0f;
#pragma unroll
  for (int reg = 0; reg < 4; ++reg) {
    size_t row = wbase + 4 * ag + reg;
    emit[row * CC + am] = acc0[reg] + bc0;
    if (am < 6) emit[row * CC + am + 16] = acc1[reg] + bc1;
  }
}

__device__ __forceinline__ float rlf(float v, int l) {
  return __int_as_float(__builtin_amdgcn_readlane(__float_as_int(v), l));
}

// ---------------- segment transfer matrices (parallel-in-time Viterbi) ----------
__global__ __launch_bounds__(256) void k_seg(const float* __restrict__ emit,
                                             const float* __restrict__ mask,
                                             const float* __restrict__ trans,
                                             float* __restrict__ phi) {
  __shared__ float Ph[2][CC][23];
  __shared__ float els[CS * CC];
  const int seg = blockIdx.x, b = blockIdx.y;
  const int tid = threadIdx.x;
  const int lane = tid & 63;
  int n = 0;  // each wave computes redundantly (no sync needed)
#pragma unroll
  for (int k = 0; k < 8; ++k)
    n += __popcll(__ballot(mask[(size_t)b * LL + k * 64 + lane] > 0.0f));
  const int t0 = seg * CS;
  for (int i = tid; i < CS * CC; i += 256)  // full 352-entry fill
    els[i] = emit[((size_t)b * LL + t0) * CC + i];
  const bool own = tid < 242;
  const int to2 = own ? tid / CC : 0;   // 0..10
  const int frm0 = own ? tid % CC : 0;  // 0..21
  float T0[CC], T1[CC];
  if (own) {
#pragma unroll
    for (int f = 0; f < CC; ++f) {
      T0[f] = trans[to2 * CC + f];
      T1[f] = trans[(to2 + 11) * CC + f];
    }
    Ph[0][to2][frm0] = (to2 == frm0) ? 0.0f : -INFINITY;
    Ph[0][to2 + 11][frm0] = (to2 + 11 == frm0) ? 0.0f : -INFINITY;
  }
  __syncthreads();
  int steps = n - t0;
  steps = steps < 0 ? 0 : (steps > CS ? CS : steps);
  int c = 0;
  for (int q = 0; q < steps; ++q) {  // block-uniform trip count
    if (own) {
      float a0 = -INFINITY, a1 = -INFINITY;
#pragma unroll
      for (int f = 0; f < CC; ++f) {
        float v = Ph[c][f][frm0];
        a0 = fmaxf(a0, v + T0[f]);
        a1 = fmaxf(a1, v + T1[f]);
      }
      Ph[c ^ 1][to2][frm0] = a0 + els[q * CC + to2];
      Ph[c ^ 1][to2 + 11][frm0] = a1 + els[q * CC + to2 + 11];
    }
    __syncthreads();
    c ^= 1;
  }
  if (own) {
    float* pb = phi + ((size_t)b * NCH + seg) * CC * CC;
    pb[to2 * CC + frm0] = Ph[c][to2][frm0];
    pb[(to2 + 11) * CC + frm0] = Ph[c][to2 + 11][frm0];
  }
}

// ---------------- compose: 32 matrix-vector max-plus steps per batch ----------
__global__ __launch_bounds__(64, 1) void k_cmp(const float* __restrict__ phi,
                                               const float* __restrict__ mask,
                                               const float* __restrict__ trans,
                                               float* __restrict__ out_score,
                                               float* __restrict__ pv,
                                               int* __restrict__ meta) {
  const int b = blockIdx.x;
  const int lane = threadIdx.x;
  const int lc = lane < CC ? lane : CC - 1;
  const float Tstop = trans[STOP_I * CC + lc];
  int n = 0;
#pragma unroll
  for (int k = 0; k < 8; ++k)
    n += __popcll(__ballot(mask[(size_t)b * LL + k * 64 + lane] > 0.0f));

  float st = (lane == START_I) ? 0.0f : NEGV;
  const float* pb = phi + (size_t)b * NCH * CC * CC;
  float row[CC], nrow[CC];
#pragma unroll
  for (int f = 0; f < CC; ++f) row[f] = pb[lc * CC + f];
  for (int s = 0; s < NCH; ++s) {
    if (lane < CC) pv[((size_t)b * NCH + s) * CC + lane] = st;
    if (s + 1 < NCH) {
#pragma unroll
      for (int f = 0; f < CC; ++f) nrow[f] = pb[((s + 1) * CC + lc) * CC + f];
    }
    float a = -INFINITY;
#pragma unroll
    for (int f = 0; f < CC; ++f) a = fmaxf(a, row[f] + rlf(st, f));
    st = a;  // identity segments preserve st exactly
#pragma unroll
    for (int f = 0; f < CC; ++f) row[f] = nrow[f];
  }

  float fin = st + Tstop;
  if (lane < CC) out_score[b * CC + lane] = fin;
  float bv = -3.0e38f;
  int bt = 0;
#pragma unroll
  for (int k = 0; k < CC; ++k) {
    float v = rlf(fin, k);
    bool g = v > bv;
    bv = g ? v : bv;
    bt = g ? k : bt;
  }
  if (lane == 0) { meta[b] = n; meta[BB + b] = bt; }
}

// ---------------- parallel replay: backpointers from checkpoints ----------------
#define RSTEP(Q, EV)                                                        \
  {                                                                         \
    const bool act = (Q) < m;                                               \
    float g0 = rlf(st, 0) + T_0,   g1 = rlf(st, 1) + T_1;                   \
    float g2 = rlf(st, 2) + T_2,   g3 = rlf(st, 3) + T_3;                   \
    float g4 = rlf(st, 4) + T_4,   g5 = rlf(st, 5) + T_5;                   \
    float g6 = rlf(st, 6) + T_6,   g7 = rlf(st, 7) + T_7;                   \
    float g8 = rlf(st, 8) + T_8,   g9 = rlf(st, 9) + T_9;                   \
    float g10 = rlf(st, 10) + T_10, g11 = rlf(st, 11) + T_11;               \
    float g12 = rlf(st, 12) + T_12, g13 = rlf(st, 13) + T_13;               \
    float g14 = rlf(st, 14) + T_14, g15 = rlf(st, 15) + T_15;               \
    float g16 = rlf(st, 16) + T_16, g17 = rlf(st, 17) + T_17;               \
    float g18 = rlf(st, 18) + T_18, g19 = rlf(st, 19) + T_19;               \
    float g20 = rlf(st, 20) + T_20, g21 = rlf(st, 21) + T_21;               \
    float m0 = fmaxf(fmaxf(g0, g1), g2);                                    \
    float m1 = fmaxf(fmaxf(g3, g4), g5);                                    \
    float m2 = fmaxf(fmaxf(g6, g7), g8);                                    \
    float m3 = fmaxf(fmaxf(g9, g10), g11);                                  \
    float m4 = fmaxf(fmaxf(g12, g13), g14);                                 \
    float m5 = fmaxf(fmaxf(g15, g16), g17);                                 \
    float m6 = fmaxf(fmaxf(g18, g19), g20);                                 \
    float n0_ = fmaxf(fmaxf(m0, m1), m2);                                   \
    float n1_ = fmaxf(fmaxf(m3, m4), m5);                                   \
    float n2_ = fmaxf(m6, g21);                                             \
    float mx = fmaxf(fmaxf(n0_, n1_), n2_);                                 \
    unsigned u = (g0 == mx ? 1u : 0u) | (g1 == mx ? 2u : 0u) |              \
                 (g2 == mx ? 4u : 0u) | (g3 == mx ? 8u : 0u) |              \
                 (g4 == mx ? 16u : 0u) | (g5 == mx ? 32u : 0u) |            \
                 (g6 == mx ? 64u : 0u) | (g7 == mx ? 128u : 0u) |           \
                 (g8 == mx ? 256u : 0u) | (g9 == mx ? 512u : 0u) |          \
                 (g10 == mx ? 1024u : 0u) | (g11 == mx ? 2048u : 0u) |      \
                 (g12 == mx ? 4096u : 0u) | (g13 == mx ? 8192u : 0u) |      \
                 (g14 == mx ? 16384u : 0u) | (g15 == mx ? 32768u : 0u) |    \
                 (g16 == mx ? 65536u : 0u) | (g17 == mx ? 131072u : 0u) |   \
                 (g18 == mx ? 262144u : 0u) | (g19 == mx ? 524288u : 0u) |  \
                 (g20 == mx ? 1048576u : 0u) | (g21 == mx ? 2097152u : 0u); \
    if (act && lane < CC) bpo[(Q)*CC] = (unsigned char)__builtin_ctz(u);    \
    st = act ? (mx + (EV)) : st;                                            \
  }

__global__ __launch_bounds__(64, 1) void k_rep(const float* __restrict__ emit,
                                               const float* __restrict__ trans,
                                               const float* __restrict__ pv,
                                               const int* __restrict__ meta,
                                               unsigned char* __restrict__ bp) {
  const int c = blockIdx.x, b = blockIdx.y;
  const int lane = threadIdx.x;
  const int n = meta[b];
  const int t0 = c * CS;
  if (t0 >= n) return;
  const int lc = lane < CC ? lane : CC - 1;
  const float* tr = trans + lc * CC;
  float T_0 = tr[0], T_1 = tr[1], T_2 = tr[2], T_3 = tr[3], T_4 = tr[4];
  float T_5 = tr[5], T_6 = tr[6], T_7 = tr[7], T_8 = tr[8], T_9 = tr[9];
  float T_10 = tr[10], T_11 = tr[11], T_12 = tr[12], T_13 = tr[13];
  float T_14 = tr[14], T_15 = tr[15], T_16 = tr[16], T_17 = tr[17];
  float T_18 = tr[18], T_19 = tr[19], T_20 = tr[20], T_21 = tr[21];
  float st = pv[((size_t)b * NCH + c) * CC + lc];
  const float* ebl = emit + ((size_t)b * LL + t0) * CC + lc;
  float e0 = ebl[0 * CC], e1 = ebl[1 * CC], e2 = ebl[2 * CC], e3 = ebl[3 * CC];
  float e4 = ebl[4 * CC], e5 = ebl[5 * CC], e6 = ebl[6 * CC], e7 = ebl[7 * CC];
  float e8 = ebl[8 * CC], e9 = ebl[9 * CC], e10 = ebl[10 * CC], e11 = ebl[11 * CC];
  float e12 = ebl[12 * CC], e13 = ebl[13 * CC], e14 = ebl[14 * CC], e15 = ebl[15 * CC];
  asm volatile(""
               : "+v"(e0), "+v"(e1), "+v"(e2), "+v"(e3), "+v"(e4), "+v"(e5),
                 "+v"(e6), "+v"(e7), "+v"(e8), "+v"(e9), "+v"(e10), "+v"(e11),
                 "+v"(e12), "+v"(e13), "+v"(e14), "+v"(e15));
  asm volatile(""
               : "+v"(T_0), "+v"(T_1), "+v"(T_2), "+v"(T_3), "+v"(T_4),
                 "+v"(T_5), "+v"(T_6), "+v"(T_7), "+v"(T_8), "+v"(T_9),
                 "+v"(T_10), "+v"(T_11), "+v"(T_12), "+v"(T_13), "+v"(T_14),
                 "+v"(T_15), "+v"(T_16), "+v"(T_17), "+v"(T_18), "+v"(T_19),
                 "+v"(T_20), "+v"(T_21));
  unsigned char* bpo = bp + ((size_t)b * LL + t0) * CC + lane;
  const int m = (n - t0) < CS ? (n - t0) : CS;
  RSTEP(0, e0)   RSTEP(1, e1)   RSTEP(2, e2)   RSTEP(3, e3)
  RSTEP(4, e4)   RSTEP(5, e5)   RSTEP(6, e6)   RSTEP(7, e7)
  RSTEP(8, e8)   RSTEP(9, e9)   RSTEP(10, e10) RSTEP(11, e11)
  RSTEP(12, e12) RSTEP(13, e13) RSTEP(14, e14) RSTEP(15, e15)
}

// ---------------- backtrace: chunk-composed backpointer maps ----------------
__global__ __launch_bounds__(64, 1) void k_back(const unsigned char* __restrict__ bp,
                                                const int* __restrict__ meta,
                                                float* __restrict__ out_path) {
  __shared__ __align__(16) unsigned char bps[LL * CC];  // 11264 B
  __shared__ unsigned char gs[64 * CC];
  const int b = blockIdx.x, lane = threadIdx.x;
  const int n = meta[b];
  const int bt = meta[BB + b];
  const uint32_t* src = (const uint32_t*)(bp + (size_t)b * LL * CC);
  uint32_t* dst = (uint32_t*)bps;
  for (int i = lane; i < (LL * CC) / 4; i += 64) dst[i] = src[i];
  __syncthreads();
  const int k = lane;
  {
    int tg0 = 0, tg1 = 1, tg2 = 2, tg3 = 3, tg4 = 4, tg5 = 5, tg6 = 6,
        tg7 = 7, tg8 = 8, tg9 = 9, tg10 = 10, tg11 = 11, tg12 = 12, tg13 = 13,
        tg14 = 14, tg15 = 15, tg16 = 16, tg17 = 17, tg18 = 18, tg19 = 19,
        tg20 = 20, tg21 = 21;
#pragma unroll
    for (int j = 7; j >= 0; --j) {
      const int t = 8 * k + j;
      const bool act = t < n;
      const unsigned char* bt_ = bps + t * CC;
      int v0 = bt_[tg0], v1 = bt_[tg1], v2 = bt_[tg2], v3 = bt_[tg3];
      int v4 = bt_[tg4], v5 = bt_[tg5], v6 = bt_[tg6], v7 = bt_[tg7];
      int v8 = bt_[tg8], v9 = bt_[tg9], v10 = bt_[tg10], v11 = bt_[tg11];
      int v12 = bt_[tg12], v13 = bt_[tg13], v14 = bt_[tg14], v15 = bt_[tg15];
      int v16 = bt_[tg16], v17 = bt_[tg17], v18 = bt_[tg18], v19 = bt_[tg19];
      int v20 = bt_[tg20], v21 = bt_[tg21];
      tg0 = act ? v0 : tg0;   tg1 = act ? v1 : tg1;
      tg2 = act ? v2 : tg2;   tg3 = act ? v3 : tg3;
      tg4 = act ? v4 : tg4;   tg5 = act ? v5 : tg5;
      tg6 = act ? v6 : tg6;   tg7 = act ? v7 : tg7;
      tg8 = act ? v8 : tg8;   tg9 = act ? v9 : tg9;
      tg10 = act ? v10 : tg10; tg11 = act ? v11 : tg11;
      tg12 = act ? v12 : tg12; tg13 = act ? v13 : tg13;
      tg14 = act ? v14 : tg14; tg15 = act ? v15 : tg15;
      tg16 = act ? v16 : tg16; tg17 = act ? v17 : tg17;
      tg18 = act ? v18 : tg18; tg19 = act ? v19 : tg19;
      tg20 = act ? v20 : tg20; tg21 = act ? v21 : tg21;
    }
    unsigned char* go = gs + k * CC;
    go[0] = (unsigned char)tg0;   go[1] = (unsigned char)tg1;
    go[2] = (unsigned char)tg2;   go[3] = (unsigned char)tg3;
    go[4] = (unsigned char)tg4;   go[5] = (unsigned char)tg5;
    go[6] = (unsigned char)tg6;   go[7] = (unsigned char)tg7;
    go[8] = (unsigned char)tg8;   go[9] = (unsigned char)tg9;
    go[10] = (unsigned char)tg10; go[11] = (unsigned char)tg11;
    go[12] = (unsigned char)tg12; go[13] = (unsigned char)tg13;
    go[14] = (unsigned char)tg14; go[15] = (unsigned char)tg15;
    go[16] = (unsigned char)tg16; go[17] = (unsigned char)tg17;
    go[18] = (unsigned char)tg18; go[19] = (unsigned char)tg19;
    go[20] = (unsigned char)tg20; go[21] = (unsigned char)tg21;
  }
  __syncthreads();
  int tag = bt, entry = bt;
  for (int kk = 63; kk >= 0; --kk) {
    if (lane == kk) entry = tag;
    tag = gs[kk * CC + tag];
  }
  tag = entry;
  float* op = out_path + (size_t)b * LL;
#pragma unroll
  for (int j = 7; j >= 0; --j) {
    int t = 8 * k + j;
    bool act = t < n;
    op[t] = act ? (float)tag : 0.0f;
    int nv = bps[t * CC + tag];
    tag = act ? nv : tag;
  }
}

extern "C" void kernel_launch(void* const* d_in, const int* in_sizes, int n_in,
                              void* d_out, int out_size, void* d_ws, size_t ws_size,
                              hipStream_t stream) {
  const float* x = (const float*)d_in[0];
  const float* mask = (const float*)d_in[1];
  const float* W = (const float*)d_in[2];
  const float* bias = (const float*)d_in[3];
  const float* trans = (const float*)d_in[4];
  float* out_score = (float*)d_out;                 // [B, C] f32
  float* out_path = (float*)d_out + BB * CC;        // [B, L] as f32 values
  char* ws = (char*)d_ws;
  float* emit = (float*)ws;
  unsigned char* bp = (unsigned char*)(ws + BP_OFF);
  int* meta = (int*)(ws + META_OFF);
  float* pvp = (float*)(ws + PV_OFF);
  float* phi = (float*)(ws + PHI_OFF);

  k_emit<<<dim3((BB * LL) / 64), dim3(256), 0, stream>>>(x, W, bias, emit);
  k_seg<<<dim3(NCH, BB), dim3(256), 0, stream>>>(emit, mask, trans, phi);
  k_cmp<<<dim3(BB), dim3(64), 0, stream>>>(phi, mask, trans, out_score, pvp, meta);
  k_rep<<<dim3(NCH, BB), dim3(64), 0, stream>>>(emit, trans, pvp, meta, bp);
  k_back<<<dim3(BB), dim3(64), 0, stream>>>(bp, meta, out_path);
}